// Round 6
// baseline (11849.888 us; speedup 1.0000x reference)
//
#include <hip/hip_runtime.h>
#include <hip/hip_bf16.h>
#include <stdint.h>

// Problem constants: B=64, T=512, V=50000, E=300, HC=512, gates=2048
#define TT 512
#define BB 64
#define HCD 512
#define NG 2048
#define EE 300
#define GBLK 32     // scan blocks; block owns 16 h-dims = 64 gate rows

typedef short bf16x8 __attribute__((ext_vector_type(8)));
typedef unsigned short u16x8 __attribute__((ext_vector_type(8)));
typedef float f32x4 __attribute__((ext_vector_type(4)));

__device__ __forceinline__ float sigf(float x) { return 1.0f / (1.0f + __expf(-x)); }
__device__ __forceinline__ float tanh_fast(float x) {
  return 1.0f - 2.0f / (__expf(2.0f * x) + 1.0f);
}
__device__ __forceinline__ unsigned short f2bf(float x) {
  __hip_bfloat16 b = __float2bfloat16(x);
  union { __hip_bfloat16 b; unsigned short u; } cv; cv.b = b; return cv.u;
}
__device__ __forceinline__ float bf2f(unsigned short u) {
  union { unsigned short u; __hip_bfloat16 b; } cv; cv.u = u; return __bfloat162float(cv.b);
}

// LLC-direct (agent-coherence-point) ops: bypass L1+L2 via sc0 sc1.
__device__ __forceinline__ void llc_store_u16(unsigned short* p, unsigned v) {
  asm volatile("global_store_short %0, %1, off sc0 sc1" :: "v"(p), "v"(v) : "memory");
}
__device__ __forceinline__ unsigned llc_load_u32(const unsigned* p) {
  unsigned r;
  asm volatile("global_load_dword %0, %1, off sc0 sc1\n\ts_waitcnt vmcnt(0)"
               : "=v"(r) : "v"(p) : "memory");
  return r;
}
__device__ __forceinline__ bf16x8 llc_load_b128(const unsigned short* p) {
  bf16x8 r;
  asm volatile("global_load_dwordx4 %0, %1, off sc0 sc1" : "=v"(r) : "v"(p) : "memory");
  return r;
}

// ---------------------------------------------------------------------------
// Kernel 1 (unchanged): xg[m=(t*64+b)][g] = emb[seq].W_ih^T + biases
// ---------------------------------------------------------------------------
#define BM 64
#define BN 64
#define BK 32

template <bool XGBF16>
__global__ __launch_bounds__(256) void xg_gemm(
    const int* __restrict__ seq, const float* __restrict__ emb,
    const float* __restrict__ W_ih, const float* __restrict__ b_ih,
    const float* __restrict__ b_hh, void* __restrict__ xg_out)
{
  __shared__ float As[BK][BM + 4];
  __shared__ float Bs[BK][BN + 4];
  __shared__ int toks[BM];

  const int tid = threadIdx.x;
  const int m0 = blockIdx.y * BM;
  const int n0 = blockIdx.x * BN;
  const int tx = tid & 15, ty = tid >> 4;

  if (tid < BM) {
    int m = m0 + tid;
    toks[tid] = seq[(m & 63) * TT + (m >> 6)];
  }

  float acc[4][4];
#pragma unroll
  for (int i = 0; i < 4; ++i)
#pragma unroll
    for (int j = 0; j < 4; ++j) acc[i][j] = 0.f;

  for (int kt = 0; kt < 10; ++kt) {
    const int k0 = kt * BK;
    __syncthreads();
#pragma unroll
    for (int p = 0; p < 2; ++p) {
      int i = tid + p * 256;
      int row = i >> 3;
      int k4 = (i & 7) * 4;
      int kg = k0 + k4;
      float4 va = make_float4(0.f, 0.f, 0.f, 0.f);
      float4 vb = make_float4(0.f, 0.f, 0.f, 0.f);
      if (kg + 3 < EE) {
        va = *(const float4*)&emb[(size_t)toks[row] * EE + kg];
        vb = *(const float4*)&W_ih[(size_t)(n0 + row) * EE + kg];
      } else {
        float a0[4] = {0.f, 0.f, 0.f, 0.f};
        float b0[4] = {0.f, 0.f, 0.f, 0.f};
#pragma unroll
        for (int e = 0; e < 4; ++e) {
          if (kg + e < EE) {
            a0[e] = emb[(size_t)toks[row] * EE + kg + e];
            b0[e] = W_ih[(size_t)(n0 + row) * EE + kg + e];
          }
        }
        va = make_float4(a0[0], a0[1], a0[2], a0[3]);
        vb = make_float4(b0[0], b0[1], b0[2], b0[3]);
      }
      As[k4 + 0][row] = va.x; As[k4 + 1][row] = va.y;
      As[k4 + 2][row] = va.z; As[k4 + 3][row] = va.w;
      Bs[k4 + 0][row] = vb.x; Bs[k4 + 1][row] = vb.y;
      Bs[k4 + 2][row] = vb.z; Bs[k4 + 3][row] = vb.w;
    }
    __syncthreads();

#pragma unroll
    for (int k = 0; k < BK; ++k) {
      float4 a = *(const float4*)&As[k][ty * 4];
      float4 b = *(const float4*)&Bs[k][tx * 4];
      float av[4] = {a.x, a.y, a.z, a.w};
      float bv[4] = {b.x, b.y, b.z, b.w};
#pragma unroll
      for (int i = 0; i < 4; ++i)
#pragma unroll
        for (int j = 0; j < 4; ++j) acc[i][j] += av[i] * bv[j];
    }
  }

  float4 bi = *(const float4*)&b_ih[n0 + tx * 4];
  float4 bh = *(const float4*)&b_hh[n0 + tx * 4];
  const float bias[4] = {bi.x + bh.x, bi.y + bh.y, bi.z + bh.z, bi.w + bh.w};

#pragma unroll
  for (int i = 0; i < 4; ++i) {
    const int m = m0 + ty * 4 + i;
    if (!XGBF16) {
      float* xg = (float*)xg_out;
      float4 o = make_float4(acc[i][0] + bias[0], acc[i][1] + bias[1],
                             acc[i][2] + bias[2], acc[i][3] + bias[3]);
      *(float4*)&xg[(size_t)m * NG + n0 + tx * 4] = o;
    } else {
      __hip_bfloat16* xg = (__hip_bfloat16*)xg_out;
#pragma unroll
      for (int e = 0; e < 4; ++e)
        xg[(size_t)m * NG + n0 + tx * 4 + e] = __float2bfloat16(acc[i][e] + bias[e]);
    }
  }
}

// ---------------------------------------------------------------------------
// Kernel 2: MFMA LSTM scan + ABLATION VARIANTS (this round is diagnostic).
// VAR 0 = real (writes d_out).
// VAR 1 = sync-only      (h-stores + drain + atomic + poll; no compute/xg/out)
// VAR 3 = sync + compute (real minus xg loads minus output stores; xgv = 0)
// VAR 2 = compute-only   (full compute + xg + out volume into scratch; NO sync)
// Variants share the same ctr lines: real raises each step-line to 32,
// VAR1 to 64, VAR3 to 96 (targets passed as arg). VAR2 ignores ctr.
// ---------------------------------------------------------------------------
template <bool XGBF16, int VAR>
__global__ __launch_bounds__(256) void lstm_scan_mfma(
    const void* __restrict__ xg_in, const float* __restrict__ W_hh,
    const int* __restrict__ lengths, float* __restrict__ out,
    unsigned short* __restrict__ hbuf, unsigned int* __restrict__ ctr,
    unsigned target)
{
  constexpr bool DO_COMPUTE = (VAR != 1);
  constexpr bool DO_SYNC    = (VAR != 2);
  constexpr bool DO_XGOUT   = (VAR == 0 || VAR == 2);

  __shared__ unsigned short Whi[64 * 512];   // 64 KB
  __shared__ unsigned short Wlo[64 * 512];   // 64 KB
  __shared__ float gLds[64][68];             // 17.4 KB

  const int tid = threadIdx.x;
  const int jb = blockIdx.x;        // 0..31
  const int lane = tid & 63;
  const int w = tid >> 6;           // wave = m-tile (16 batches)
  const int r15 = lane & 15;
  const int q4 = lane >> 4;

  if (DO_COMPUTE) {
    for (int i = tid; i < 64 * 64; i += 256) {
      const int n = i >> 6;
      const int c = i & 63;
      const int growg = (n >> 4) * HCD + jb * 16 + (n & 15);
      const float* src = &W_hh[(size_t)growg * HCD + c * 8];
      u16x8 hi, lo;
#pragma unroll
      for (int e = 0; e < 8; ++e) {
        float wv = src[e];
        unsigned short wh = f2bf(wv);
        hi[e] = wh;
        lo[e] = f2bf(wv - bf2f(wh));
      }
      const int cs = c ^ (n & 7);
      *(u16x8*)&Whi[(n * 64 + cs) * 8] = hi;
      *(u16x8*)&Wlo[(n * 64 + cs) * 8] = lo;
    }
  } else {
    // keep LDS allocation identical (occupancy parity with real)
    if (tid == 0) { gLds[0][0] = 0.f; Whi[0] = 0; Wlo[0] = 0; }
  }

  const int d = tid & 15;
  const int bq = tid >> 4;          // 0..15
  const int dglob = jb * 16 + d;
  float hst[4] = {0.f, 0.f, 0.f, 0.f};
  float cst[4] = {0.f, 0.f, 0.f, 0.f};
  int lenq[4];
#pragma unroll
  for (int q = 0; q < 4; ++q) lenq[q] = lengths[bq + q * 16];

  float* outH = out;
  float* outC = out + (size_t)BB * TT * HCD;
  float* outh = out + (size_t)2 * BB * TT * HCD;
  float* outc = outh + (size_t)BB * HCD;

  const int abase = r15 * HCD + q4 * 8;

  float xgv[4][4];
#pragma unroll
  for (int q = 0; q < 4; ++q)
#pragma unroll
    for (int g = 0; g < 4; ++g) xgv[q][g] = 0.f;
  if (DO_XGOUT) {
#pragma unroll
    for (int q = 0; q < 4; ++q)
#pragma unroll
      for (int g = 0; g < 4; ++g) {
        const size_t xi = (size_t)(bq + q * 16) * NG + (size_t)g * HCD + dglob;
        xgv[q][g] = XGBF16 ? bf2f(((const unsigned short*)xg_in)[xi])
                           : ((const float*)xg_in)[xi];
      }
  }

  __syncthreads();

  for (int t = 0; t < TT; ++t) {
    const int rb = t & 1;
    const unsigned short* hsrc = hbuf + rb * (BB * HCD);
    unsigned short* hdst = hbuf + (rb ^ 1) * (BB * HCD);

    if (DO_COMPUTE) {
      bf16x8 a[16];
      {
        const unsigned short* p = hsrc + (size_t)w * 16 * HCD + abase;
#pragma unroll
        for (int kt = 0; kt < 16; ++kt) a[kt] = llc_load_b128(p + kt * 32);
      }
      asm volatile("s_waitcnt vmcnt(0)" ::: "memory");
      __builtin_amdgcn_sched_barrier(0);   // rule #18

      f32x4 acch[4], accl[4];
#pragma unroll
      for (int n = 0; n < 4; ++n) { acch[n] = {0.f,0.f,0.f,0.f}; accl[n] = {0.f,0.f,0.f,0.f}; }
#pragma unroll
      for (int kt = 0; kt < 16; ++kt) {
#pragma unroll
        for (int n = 0; n < 4; ++n) {
          const int row = n * 16 + r15;
          const int cs = ((kt * 4 + q4) ^ (row & 7)) * 8;
          bf16x8 bh = *(const bf16x8*)&Whi[row * 512 + cs];
          bf16x8 bl = *(const bf16x8*)&Wlo[row * 512 + cs];
          acch[n] = __builtin_amdgcn_mfma_f32_16x16x32_bf16(a[kt], bh, acch[n], 0, 0, 0);
          accl[n] = __builtin_amdgcn_mfma_f32_16x16x32_bf16(a[kt], bl, accl[n], 0, 0, 0);
        }
      }
#pragma unroll
      for (int n = 0; n < 4; ++n)
#pragma unroll
        for (int r = 0; r < 4; ++r)
          gLds[w * 16 + q4 * 4 + r][n * 16 + r15] = acch[n][r] + accl[n][r];
      __syncthreads();
    }

    float ho[4], co[4];
    if (DO_COMPUTE) {
#pragma unroll
      for (int q = 0; q < 4; ++q) {
        const int b = bq + q * 16;
        float gi = gLds[b][d]      + xgv[q][0];
        float gf = gLds[b][16 + d] + xgv[q][1];
        float gg = gLds[b][32 + d] + xgv[q][2];
        float go = gLds[b][48 + d] + xgv[q][3];
        float iv = sigf(gi), fv = sigf(gf), gv = tanh_fast(gg), ov = sigf(go);
        float cn = fv * cst[q] + iv * gv;
        float hn = ov * tanh_fast(cn);
        const bool m = (t < lenq[q]);
        ho[q] = m ? hn : 0.f;
        co[q] = m ? cn : 0.f;
        hst[q] = m ? hn : hst[q];
        cst[q] = m ? cn : cst[q];
        llc_store_u16(&hdst[(size_t)b * HCD + dglob], (unsigned)f2bf(hst[q]));
      }
    } else {
      // VAR1: same store volume/pattern, trivial values
#pragma unroll
      for (int q = 0; q < 4; ++q)
        llc_store_u16(&hdst[(size_t)(bq + q * 16) * HCD + dglob],
                      (unsigned)f2bf((float)t));
    }

    if (DO_SYNC) {
      asm volatile("s_waitcnt vmcnt(0)" ::: "memory");
      __syncthreads();
      if (tid == 0) atomicAdd(&ctr[(size_t)t * 32], 1u);
    } else {
      __syncthreads();   // block-local LDS reuse barrier only
    }

    if (DO_XGOUT) {
#pragma unroll
      for (int q = 0; q < 4; ++q) {
        const int b = bq + q * 16;
        outH[((size_t)b * TT + t) * HCD + dglob] = ho[q];
        outC[((size_t)b * TT + t) * HCD + dglob] = co[q];
      }
      if (t < TT - 1) {
#pragma unroll
        for (int q = 0; q < 4; ++q)
#pragma unroll
          for (int g = 0; g < 4; ++g) {
            const size_t xi = ((size_t)(t + 1) * BB + (bq + q * 16)) * NG
                              + (size_t)g * HCD + dglob;
            xgv[q][g] = XGBF16 ? bf2f(((const unsigned short*)xg_in)[xi])
                               : ((const float*)xg_in)[xi];
          }
      }
    }

    if (DO_SYNC && t < TT - 1) {
      if (tid == 0) {
        int spin = 0;
        while (llc_load_u32(&ctr[(size_t)t * 32]) < target) {
          __builtin_amdgcn_s_sleep(2);
          if (++spin > (1 << 22)) break;   // hang guard
        }
      }
      __syncthreads();
    }
  }

  if (VAR == 0) {
#pragma unroll
    for (int q = 0; q < 4; ++q) {
      const int b = bq + q * 16;
      outh[(size_t)b * HCD + dglob] = hst[q];
      outc[(size_t)b * HCD + dglob] = cst[q];
    }
  }
}

// ---------------------------------------------------------------------------
// Workspace layout:
//   [0, 65536)         : ctr (512 steps x 32 u32, 128B stride) -- zeroed
//   [65536, 196608)    : hbuf (2 x 64 x 512 bf16)              -- zeroed
//   [196608, ...)      : xg (32768 x 2048, f32 or bf16); reused as VAR2 sink
// Launch order: xg_gemm -> VAR0(real,d_out) -> VAR1 -> VAR3 -> VAR2(scribbles xg)
// ---------------------------------------------------------------------------
extern "C" void kernel_launch(void* const* d_in, const int* in_sizes, int n_in,
                              void* d_out, int out_size, void* d_ws, size_t ws_size,
                              hipStream_t stream) {
  const int*   seq  = (const int*)d_in[0];
  const int*   len  = (const int*)d_in[1];
  const float* emb  = (const float*)d_in[2];
  const float* W_ih = (const float*)d_in[3];
  const float* W_hh = (const float*)d_in[4];
  const float* b_ih = (const float*)d_in[5];
  const float* b_hh = (const float*)d_in[6];
  float* out = (float*)d_out;

  unsigned int* ctr = (unsigned int*)d_ws;
  unsigned short* hbuf = (unsigned short*)((char*)d_ws + 65536);
  void* xg = (void*)((char*)d_ws + 196608);
  float* sink = (float*)xg;   // VAR2 writes here (region free after real scan)

  const size_t need_f32  = 196608ULL + (size_t)32768 * 2048 * 4;
  const size_t need_bf16 = 196608ULL + (size_t)32768 * 2048 * 2;

  bool bf16path;
  if (ws_size >= need_f32)       bf16path = false;
  else if (ws_size >= need_bf16) bf16path = true;
  else                           return;

  hipMemsetAsync(d_ws, 0, 196608, stream);  // ctr + hbuf (both halves)

  dim3 g1(NG / BN, (TT * BB) / BM);  // (32, 512)
  if (!bf16path) {
    xg_gemm<false><<<g1, 256, 0, stream>>>(seq, emb, W_ih, b_ih, b_hh, xg);
    lstm_scan_mfma<false, 0><<<GBLK, 256, 0, stream>>>(xg, W_hh, len, out,  hbuf, ctr, 32u);
    lstm_scan_mfma<false, 1><<<GBLK, 256, 0, stream>>>(xg, W_hh, len, sink, hbuf, ctr, 64u);
    lstm_scan_mfma<false, 3><<<GBLK, 256, 0, stream>>>(xg, W_hh, len, sink, hbuf, ctr, 96u);
    lstm_scan_mfma<false, 2><<<GBLK, 256, 0, stream>>>(xg, W_hh, len, sink, hbuf, ctr, 0u);
  } else {
    xg_gemm<true><<<g1, 256, 0, stream>>>(seq, emb, W_ih, b_ih, b_hh, xg);
    lstm_scan_mfma<true, 0><<<GBLK, 256, 0, stream>>>(xg, W_hh, len, out,  hbuf, ctr, 32u);
    lstm_scan_mfma<true, 1><<<GBLK, 256, 0, stream>>>(xg, W_hh, len, sink, hbuf, ctr, 64u);
    lstm_scan_mfma<true, 3><<<GBLK, 256, 0, stream>>>(xg, W_hh, len, sink, hbuf, ctr, 96u);
    lstm_scan_mfma<true, 2><<<GBLK, 256, 0, stream>>>(xg, W_hh, len, sink, hbuf, ctr, 0u);
  }
}

// Round 7
// 3565.648 us; speedup vs baseline: 3.3233x; 3.3233x over previous
//
#include <hip/hip_runtime.h>
#include <hip/hip_bf16.h>
#include <stdint.h>

// Problem constants: B=64, T=512, V=50000, E=300, HC=512, gates=2048
#define TT 512
#define BB 64
#define HCD 512
#define NG 2048
#define EE 300

// Scan geometry: 2 independent batch-groups x 16 blocks (batch recurrences
// are independent; only weights are shared). Block owns 32 h-dims = 128 gate
// rows: W_hi bf16 in LDS (128KB), W_lo bf16 in VGPRs (128/lane).
#define NGRP 2
#define PBLK 16
#define MB   32     // batches per group
#define DPB  32     // dims per block

typedef short bf16x8 __attribute__((ext_vector_type(8)));
typedef unsigned short u16x8 __attribute__((ext_vector_type(8)));
typedef float f32x4 __attribute__((ext_vector_type(4)));

__device__ __forceinline__ float sigf(float x) { return 1.0f / (1.0f + __expf(-x)); }
__device__ __forceinline__ float tanh_fast(float x) {
  return 1.0f - 2.0f / (__expf(2.0f * x) + 1.0f);
}
__device__ __forceinline__ unsigned short f2bf(float x) {
  __hip_bfloat16 b = __float2bfloat16(x);
  union { __hip_bfloat16 b; unsigned short u; } cv; cv.b = b; return cv.u;
}
__device__ __forceinline__ float bf2f(unsigned short u) {
  union { unsigned short u; __hip_bfloat16 b; } cv; cv.u = u; return __bfloat162float(cv.b);
}

// LLC-direct (agent-coherence-point) ops: bypass L1+L2 via sc0 sc1.
__device__ __forceinline__ void llc_store_u16(unsigned short* p, unsigned v) {
  asm volatile("global_store_short %0, %1, off sc0 sc1" :: "v"(p), "v"(v) : "memory");
}
__device__ __forceinline__ void llc_store_u32(unsigned* p, unsigned v) {
  asm volatile("global_store_dword %0, %1, off sc0 sc1" :: "v"(p), "v"(v) : "memory");
}
__device__ __forceinline__ unsigned llc_load_u32(const unsigned* p) {
  unsigned r;
  asm volatile("global_load_dword %0, %1, off sc0 sc1\n\ts_waitcnt vmcnt(0)"
               : "=v"(r) : "v"(p) : "memory");
  return r;
}
__device__ __forceinline__ bf16x8 llc_load_b128(const unsigned short* p) {
  bf16x8 r;
  asm volatile("global_load_dwordx4 %0, %1, off sc0 sc1" : "=v"(r) : "v"(p) : "memory");
  return r;
}

// ---------------------------------------------------------------------------
// Kernel 1 (unchanged): xg[m=(t*64+b)][g] = emb[seq].W_ih^T + biases
// ---------------------------------------------------------------------------
#define BM 64
#define BN 64
#define BK 32

template <bool XGBF16>
__global__ __launch_bounds__(256) void xg_gemm(
    const int* __restrict__ seq, const float* __restrict__ emb,
    const float* __restrict__ W_ih, const float* __restrict__ b_ih,
    const float* __restrict__ b_hh, void* __restrict__ xg_out)
{
  __shared__ float As[BK][BM + 4];
  __shared__ float Bs[BK][BN + 4];
  __shared__ int toks[BM];

  const int tid = threadIdx.x;
  const int m0 = blockIdx.y * BM;
  const int n0 = blockIdx.x * BN;
  const int tx = tid & 15, ty = tid >> 4;

  if (tid < BM) {
    int m = m0 + tid;
    toks[tid] = seq[(m & 63) * TT + (m >> 6)];
  }

  float acc[4][4];
#pragma unroll
  for (int i = 0; i < 4; ++i)
#pragma unroll
    for (int j = 0; j < 4; ++j) acc[i][j] = 0.f;

  for (int kt = 0; kt < 10; ++kt) {
    const int k0 = kt * BK;
    __syncthreads();
#pragma unroll
    for (int p = 0; p < 2; ++p) {
      int i = tid + p * 256;
      int row = i >> 3;
      int k4 = (i & 7) * 4;
      int kg = k0 + k4;
      float4 va = make_float4(0.f, 0.f, 0.f, 0.f);
      float4 vb = make_float4(0.f, 0.f, 0.f, 0.f);
      if (kg + 3 < EE) {
        va = *(const float4*)&emb[(size_t)toks[row] * EE + kg];
        vb = *(const float4*)&W_ih[(size_t)(n0 + row) * EE + kg];
      } else {
        float a0[4] = {0.f, 0.f, 0.f, 0.f};
        float b0[4] = {0.f, 0.f, 0.f, 0.f};
#pragma unroll
        for (int e = 0; e < 4; ++e) {
          if (kg + e < EE) {
            a0[e] = emb[(size_t)toks[row] * EE + kg + e];
            b0[e] = W_ih[(size_t)(n0 + row) * EE + kg + e];
          }
        }
        va = make_float4(a0[0], a0[1], a0[2], a0[3]);
        vb = make_float4(b0[0], b0[1], b0[2], b0[3]);
      }
      As[k4 + 0][row] = va.x; As[k4 + 1][row] = va.y;
      As[k4 + 2][row] = va.z; As[k4 + 3][row] = va.w;
      Bs[k4 + 0][row] = vb.x; Bs[k4 + 1][row] = vb.y;
      Bs[k4 + 2][row] = vb.z; Bs[k4 + 3][row] = vb.w;
    }
    __syncthreads();

#pragma unroll
    for (int k = 0; k < BK; ++k) {
      float4 a = *(const float4*)&As[k][ty * 4];
      float4 b = *(const float4*)&Bs[k][tx * 4];
      float av[4] = {a.x, a.y, a.z, a.w};
      float bv[4] = {b.x, b.y, b.z, b.w};
#pragma unroll
      for (int i = 0; i < 4; ++i)
#pragma unroll
        for (int j = 0; j < 4; ++j) acc[i][j] += av[i] * bv[j];
    }
  }

  float4 bi = *(const float4*)&b_ih[n0 + tx * 4];
  float4 bh = *(const float4*)&b_hh[n0 + tx * 4];
  const float bias[4] = {bi.x + bh.x, bi.y + bh.y, bi.z + bh.z, bi.w + bh.w};

#pragma unroll
  for (int i = 0; i < 4; ++i) {
    const int m = m0 + ty * 4 + i;
    if (!XGBF16) {
      float* xg = (float*)xg_out;
      float4 o = make_float4(acc[i][0] + bias[0], acc[i][1] + bias[1],
                             acc[i][2] + bias[2], acc[i][3] + bias[3]);
      *(float4*)&xg[(size_t)m * NG + n0 + tx * 4] = o;
    } else {
      __hip_bfloat16* xg = (__hip_bfloat16*)xg_out;
#pragma unroll
      for (int e = 0; e < 4; ++e)
        xg[(size_t)m * NG + n0 + tx * 4 + e] = __float2bfloat16(acc[i][e] + bias[e]);
    }
  }
}

// ---------------------------------------------------------------------------
// Kernel 2: batch-split MFMA LSTM scan. 32 blocks = 2 groups x 16.
// Group g owns batches [g*32, g*32+32) — NO cross-group coupling.
// Block p in group owns dims [p*32, p*32+32) -> 128 gate rows:
//   W_hi (bf16) in LDS 128KB, swizzled; W_lo (bf16) in VGPRs (2x16 frags).
// Per step: stage h (32KB) LLC->LDS (union w/ gates buffer), MFMA
// gates = h @ (Whi + Wlo)^T (wave w = gate w), state update, publish h via
// LLC stores, store-only per-block flag, 16-lane parallel poll (no RMW).
// ---------------------------------------------------------------------------
template <bool XGBF16>
__global__ __launch_bounds__(256) void lstm_scan_mfma(
    const void* __restrict__ xg_in, const float* __restrict__ W_hh,
    const int* __restrict__ lengths, float* __restrict__ out,
    unsigned short* __restrict__ hbuf, unsigned int* __restrict__ flags)
{
  __shared__ unsigned short Whi[128 * 512];                 // 131072 B
  __shared__ __align__(16) unsigned char Ubuf[32 * 1024];   // 32768 B (A / gates union)
  unsigned short* Albs = (unsigned short*)Ubuf;             // A: 32 x 64 chunks x 8 bf16
  float (*gLds)[132] = (float (*)[132])Ubuf;                // gates: 32 x 132 f32 (16.9KB)

  const int tid = threadIdx.x;
  const int bid = blockIdx.x;
  const int gid = bid >> 4;        // group 0..1
  const int p   = bid & 15;        // block in group
  const int lane = tid & 63;
  const int w = tid >> 6;          // wave = gate index 0..3
  const int r15 = lane & 15;
  const int q4 = lane >> 4;

  // ---- stage W_hi -> LDS (128 rows = gate g x dim dl), chunk-XOR swizzled
  for (int i = tid; i < 128 * 64; i += 256) {
    const int n = i >> 6;          // local row: g = n>>5, dl = n&31
    const int c = i & 63;
    const int grow = (n >> 5) * HCD + p * DPB + (n & 31);
    const float* src = &W_hh[(size_t)grow * HCD + c * 8];
    u16x8 hi;
#pragma unroll
    for (int e = 0; e < 8; ++e) hi[e] = f2bf(src[e]);
    *(u16x8*)&Whi[(n * 64 + (c ^ (n & 7))) * 8] = hi;
  }

  // ---- W_lo -> VGPRs: wave w's 32 rows as MFMA B-frags (nt, kt), static idx
  bf16x8 wlo[2][16];
#pragma unroll
  for (int nt = 0; nt < 2; ++nt) {
    const int grow = w * HCD + p * DPB + nt * 16 + r15;
#pragma unroll
    for (int kt = 0; kt < 16; ++kt) {
      const float* src = &W_hh[(size_t)grow * HCD + kt * 32 + q4 * 8];
      bf16x8 lo;
#pragma unroll
      for (int e = 0; e < 8; ++e) {
        float wv = src[e];
        lo[e] = (short)f2bf(wv - bf2f(f2bf(wv)));
      }
      wlo[nt][kt] = lo;
    }
  }

  // state threads: 4 cells each: (dim dl, batches bq + {0,8,16,24})
  const int dl = tid & 31;
  const int bq = tid >> 5;         // 0..7
  const int dglob = p * DPB + dl;
  float hst[4] = {0.f, 0.f, 0.f, 0.f};
  float cst[4] = {0.f, 0.f, 0.f, 0.f};
  int lenq[4];
#pragma unroll
  for (int q = 0; q < 4; ++q) lenq[q] = lengths[gid * MB + bq + q * 8];

  float* outH = out;
  float* outC = out + (size_t)BB * TT * HCD;
  float* outh = out + (size_t)2 * BB * TT * HCD;
  float* outc = outh + (size_t)BB * HCD;

  // xg(0) prefetch
  float xgv[4][4];
#pragma unroll
  for (int q = 0; q < 4; ++q)
#pragma unroll
    for (int g = 0; g < 4; ++g) {
      const size_t xi = (size_t)(gid * MB + bq + q * 8) * NG + (size_t)g * HCD + dglob;
      xgv[q][g] = XGBF16 ? bf2f(((const unsigned short*)xg_in)[xi])
                         : ((const float*)xg_in)[xi];
    }

  __syncthreads();

  for (int t = 0; t < TT; ++t) {
    const unsigned short* hsrcg = hbuf + (t & 1) * (BB * HCD) + gid * MB * HCD;
    unsigned short* hdst = hbuf + ((t & 1) ^ 1) * (BB * HCD);

    // ---- stage A (group's 32 batches of h(t-1)): LLC -> LDS, swizzled
    {
      bf16x8 v[8];
#pragma unroll
      for (int k = 0; k < 8; ++k) {
        const int ci = tid + k * 256;
        const int m = ci >> 6, c = ci & 63;
        v[k] = llc_load_b128(hsrcg + m * HCD + c * 8);
      }
      asm volatile("s_waitcnt vmcnt(0)" ::: "memory");
      __builtin_amdgcn_sched_barrier(0);   // rule #18: writes must not hoist
#pragma unroll
      for (int k = 0; k < 8; ++k) {
        const int ci = tid + k * 256;
        const int m = ci >> 6, c = ci & 63;
        *(bf16x8*)&Albs[(m * 64 + (c ^ (m & 7))) * 8] = v[k];
      }
    }
    __syncthreads();

    // ---- MFMA: gates = h @ (Whi + Wlo)^T ; wave w covers gate w (32 rows)
    f32x4 ah[2][2], al[2][2];
#pragma unroll
    for (int mt = 0; mt < 2; ++mt)
#pragma unroll
      for (int nt = 0; nt < 2; ++nt) { ah[mt][nt] = {0.f,0.f,0.f,0.f}; al[mt][nt] = {0.f,0.f,0.f,0.f}; }
#pragma unroll
    for (int kt = 0; kt < 16; ++kt) {
      bf16x8 af[2];
#pragma unroll
      for (int mt = 0; mt < 2; ++mt) {
        const int m = mt * 16 + r15;
        af[mt] = *(const bf16x8*)&Albs[(m * 64 + ((kt * 4 + q4) ^ (m & 7))) * 8];
      }
#pragma unroll
      for (int nt = 0; nt < 2; ++nt) {
        const int nl = w * 32 + nt * 16 + r15;
        bf16x8 bh = *(const bf16x8*)&Whi[(nl * 64 + ((kt * 4 + q4) ^ (nl & 7))) * 8];
#pragma unroll
        for (int mt = 0; mt < 2; ++mt) {
          ah[mt][nt] = __builtin_amdgcn_mfma_f32_16x16x32_bf16(af[mt], bh,          ah[mt][nt], 0, 0, 0);
          al[mt][nt] = __builtin_amdgcn_mfma_f32_16x16x32_bf16(af[mt], wlo[nt][kt], al[mt][nt], 0, 0, 0);
        }
      }
    }
    __syncthreads();   // all A-frag reads done; Ubuf becomes the gates buffer

    // D layout (m89): row m = q4*4 + r (batch), col = r15 (within 16x16)
#pragma unroll
    for (int mt = 0; mt < 2; ++mt)
#pragma unroll
      for (int nt = 0; nt < 2; ++nt)
#pragma unroll
        for (int r = 0; r < 4; ++r)
          gLds[mt * 16 + q4 * 4 + r][w * 32 + nt * 16 + r15] = ah[mt][nt][r] + al[mt][nt][r];
    __syncthreads();

    // ---- state update (gate g at col g*32 + dl)
    float ho[4], co[4];
#pragma unroll
    for (int q = 0; q < 4; ++q) {
      const int bl = bq + q * 8;
      float gi = gLds[bl][dl];
      float gf = gLds[bl][32 + dl];
      float gg = gLds[bl][64 + dl];
      float go = gLds[bl][96 + dl];
      float iv = sigf(gi + xgv[q][0]), fv = sigf(gf + xgv[q][1]);
      float gv = tanh_fast(gg + xgv[q][2]), ov = sigf(go + xgv[q][3]);
      float cn = fv * cst[q] + iv * gv;
      float hn = ov * tanh_fast(cn);
      const bool m = (t < lenq[q]);
      ho[q] = m ? hn : 0.f;
      co[q] = m ? cn : 0.f;
      hst[q] = m ? hn : hst[q];
      cst[q] = m ? cn : cst[q];
      llc_store_u16(&hdst[(size_t)(gid * MB + bl) * HCD + dglob], (unsigned)f2bf(hst[q]));
    }

    // drain h-stores (per wave), then block-wide arrival
    asm volatile("s_waitcnt vmcnt(0)" ::: "memory");
    __syncthreads();

    if (t < TT - 1) {
      if (tid == 0)
        llc_store_u32(&flags[(gid * PBLK + p) * 16], (unsigned)(t + 1));  // own line, no RMW

      // off-critical-path: output stores + xg(t+1) prefetch
#pragma unroll
      for (int q = 0; q < 4; ++q) {
        const int bg = gid * MB + bq + q * 8;
        outH[((size_t)bg * TT + t) * HCD + dglob] = ho[q];
        outC[((size_t)bg * TT + t) * HCD + dglob] = co[q];
      }
#pragma unroll
      for (int q = 0; q < 4; ++q)
#pragma unroll
        for (int g = 0; g < 4; ++g) {
          const size_t xi = ((size_t)(t + 1) * BB + (gid * MB + bq + q * 8)) * NG
                            + (size_t)g * HCD + dglob;
          xgv[q][g] = XGBF16 ? bf2f(((const unsigned short*)xg_in)[xi])
                             : ((const float*)xg_in)[xi];
        }

      // 16-line parallel poll (wave 0), store-only flags, __all ballot
      if (w == 0) {
        const unsigned tgt = (unsigned)(t + 1);
        int spin = 0;
        for (;;) {
          unsigned fl = llc_load_u32(&flags[(gid * PBLK + (lane & 15)) * 16]);
          if (__all(fl >= tgt)) break;
          __builtin_amdgcn_s_sleep(1);
          if (++spin > (1 << 22)) break;   // hang guard
        }
      }
      __syncthreads();
    } else {
#pragma unroll
      for (int q = 0; q < 4; ++q) {
        const int bg = gid * MB + bq + q * 8;
        outH[((size_t)bg * TT + t) * HCD + dglob] = ho[q];
        outC[((size_t)bg * TT + t) * HCD + dglob] = co[q];
      }
    }
  }

#pragma unroll
  for (int q = 0; q < 4; ++q) {
    const int bg = gid * MB + bq + q * 8;
    outh[(size_t)bg * HCD + dglob] = hst[q];
    outc[(size_t)bg * HCD + dglob] = cst[q];
  }
}

// ---------------------------------------------------------------------------
// Workspace layout:
//   [0, 65536)         : flags (32 blocks x 64B-strided u32) -- zeroed
//   [65536, 196608)    : hbuf (2 x 64 x 512 bf16)            -- zeroed
//   [196608, ...)      : xg (32768 x 2048, f32 or bf16)
// ---------------------------------------------------------------------------
extern "C" void kernel_launch(void* const* d_in, const int* in_sizes, int n_in,
                              void* d_out, int out_size, void* d_ws, size_t ws_size,
                              hipStream_t stream) {
  const int*   seq  = (const int*)d_in[0];
  const int*   len  = (const int*)d_in[1];
  const float* emb  = (const float*)d_in[2];
  const float* W_ih = (const float*)d_in[3];
  const float* W_hh = (const float*)d_in[4];
  const float* b_ih = (const float*)d_in[5];
  const float* b_hh = (const float*)d_in[6];
  float* out = (float*)d_out;

  unsigned int* flags = (unsigned int*)d_ws;
  unsigned short* hbuf = (unsigned short*)((char*)d_ws + 65536);
  void* xg = (void*)((char*)d_ws + 196608);

  const size_t need_f32  = 196608ULL + (size_t)32768 * 2048 * 4;
  const size_t need_bf16 = 196608ULL + (size_t)32768 * 2048 * 2;

  bool bf16path;
  if (ws_size >= need_f32)       bf16path = false;
  else if (ws_size >= need_bf16) bf16path = true;
  else                           return;

  hipMemsetAsync(d_ws, 0, 196608, stream);  // flags + hbuf (both halves)

  dim3 g1(NG / BN, (TT * BB) / BM);  // (32, 512)
  if (!bf16path) {
    xg_gemm<false><<<g1, 256, 0, stream>>>(seq, emb, W_ih, b_ih, b_hh, xg);
    lstm_scan_mfma<false><<<NGRP * PBLK, 256, 0, stream>>>(xg, W_hh, len, out, hbuf, flags);
  } else {
    xg_gemm<true><<<g1, 256, 0, stream>>>(seq, emb, W_ih, b_ih, b_hh, xg);
    lstm_scan_mfma<true><<<NGRP * PBLK, 256, 0, stream>>>(xg, W_hh, len, out, hbuf, flags);
  }
}